// Round 10
// baseline (109.590 us; speedup 1.0000x reference)
//
#include <hip/hip_runtime.h>

// Causal linear attention (ELU+1), chunked prefix-scan, 3-kernel pipeline,
// matmuls on bf16 MFMA (v_mfma_f32_16x16x32_bf16), fp32 accumulate.
// Shapes: q,k,v,out = [B=2, T=2048, H=16, D=64] fp32, layout [B,T,H,D].
//
// R9 state: 109 us total; ~42 us is harness ws-poison in the timed path,
// kernels ~60 us vs ~22 us traffic floor. k_out staging identified as the
// biggest compressible cost (fp32 K/V re-read, phi recompute, V^T scatter).
// R10: k_state exports phiK (natural) + V^T as bf16; k_out stages K/V/S as
// raw ushort8 copies. Only Q needs phi+cvt in k_out.
//
// Fragment conventions (gfx950 16x16x32 bf16):
//   A-frag: lane = m + 16*kblk holds A[m][kblk*8+i]        (read ROW m of tile)
//   B-frag: lane = n + 16*kblk holds B[kblk*8+i][n]        (read ROW n of B^T tile)
//   C/D:    lane holds D[(lane>>4)*4+j][lane&15]           (verified m89)

#define BQ 2
#define TT 2048
#define HH 16
#define DD 64
#define CC 64
#define NC (TT / CC)      // 32 chunks per (b,h)
#define BH (BQ * HH)      // 32
#define NCH (BH * NC)     // 1024 chunk-blocks
#define LDU 72            // ushort stride: 144B rows (16B-aligned, bank-skewed)

typedef __attribute__((ext_vector_type(8))) short short8;
typedef __attribute__((ext_vector_type(4))) float f32x4;

__device__ __forceinline__ float phi_f(float x) {
    return x > 0.f ? x + 1.f : __expf(x);   // elu(x)+1
}
__device__ __forceinline__ unsigned short f2bf(float f) {   // fp32 -> bf16 RNE
    unsigned int u = __float_as_uint(f);
    u += 0x7FFFu + ((u >> 16) & 1u);
    return (unsigned short)(u >> 16);
}
__device__ __forceinline__ float bf2f(unsigned short s) {
    return __uint_as_float(((unsigned int)s) << 16);
}

// ---- Phase 1: per-chunk deltas; exports dS^T, phiK (natural), V^T (all bf16) ----
__global__ __launch_bounds__(256, 4) void k_state(const float* __restrict__ K,
                                                  const float* __restrict__ V,
                                                  unsigned short* __restrict__ wsSh,
                                                  unsigned short* __restrict__ wsKb,
                                                  unsigned short* __restrict__ wsVt,
                                                  float* __restrict__ wsZ) {
    __shared__ __align__(16) unsigned short Kt[DD][LDU];   // phiK^T: Kt[d][t]
    __shared__ __align__(16) unsigned short Vt[DD][LDU];   // V^T:    Vt[e][t]

    const int cid = blockIdx.x;
    const int bh = cid / NC, c = cid % NC;
    const int b = bh / HH, h = bh % HH;
    const int t0 = c * CC;
    const int tid = threadIdx.x;

#pragma unroll
    for (int w = 0; w < 4; ++w) {
        const int idx = tid + (w << 8);
        const int r = idx >> 4, q4 = (idx & 15) << 2;   // r = t-row, q4 = d/e quad
        const int g = (((b * TT + t0 + r) * HH + h) << 6) + q4;
        const float4 kv = *(const float4*)(K + g);
        ushort4 pk;
        pk.x = f2bf(phi_f(kv.x)); pk.y = f2bf(phi_f(kv.y));
        pk.z = f2bf(phi_f(kv.z)); pk.w = f2bf(phi_f(kv.w));
        Kt[q4 + 0][r] = pk.x; Kt[q4 + 1][r] = pk.y;
        Kt[q4 + 2][r] = pk.z; Kt[q4 + 3][r] = pk.w;
        // export phiK natural layout (coalesced 8B/thread)
        *(ushort4*)(wsKb + (size_t)cid * (DD * CC) + r * DD + q4) = pk;
        const float4 vv = *(const float4*)(V + g);
        Vt[q4 + 0][r] = f2bf(vv.x);
        Vt[q4 + 1][r] = f2bf(vv.y);
        Vt[q4 + 2][r] = f2bf(vv.z);
        Vt[q4 + 3][r] = f2bf(vv.w);
    }
    __syncthreads();

    const int wid = tid >> 6, lane = tid & 63;
    const int rg = lane >> 4, cl = lane & 15;

    // dS^T[e][d] = sum_t V[t][e] * phiK[t][d] ; wave wid owns e-band 16*wid..+15
    f32x4 zero4 = {0.f, 0.f, 0.f, 0.f};
    f32x4 acc[4] = {zero4, zero4, zero4, zero4};
#pragma unroll
    for (int kk = 0; kk < 2; ++kk) {
        const short8 a = *(const short8*)&Vt[16 * wid + cl][kk * 32 + rg * 8];
#pragma unroll
        for (int nt = 0; nt < 4; ++nt) {
            const short8 bb = *(const short8*)&Kt[16 * nt + cl][kk * 32 + rg * 8];
            acc[nt] = __builtin_amdgcn_mfma_f32_16x16x32_bf16(a, bb, acc[nt], 0, 0, 0);
        }
    }

    // export V^T rows (coalesced ushort8 copies from LDS)
#pragma unroll
    for (int w = 0; w < 2; ++w) {
        const int idx2 = tid + (w << 8);                   // 0..511
        const int rr = idx2 >> 3, c8 = (idx2 & 7) << 3;    // row, col-octet
        *(short8*)(wsVt + (size_t)cid * (DD * CC) + rr * CC + c8) =
            *(const short8*)&Vt[rr][c8];
    }

    // z[d] = sum_t phiK[t][d]  (tid<64: one row of Kt per thread)
    if (tid < DD) {
        float s = 0.f;
#pragma unroll
        for (int tb = 0; tb < 8; ++tb) {
            const short8 v = *(const short8*)&Kt[tid][tb * 8];
#pragma unroll
            for (int i = 0; i < 8; ++i) s += bf2f((unsigned short)v[i]);
        }
        wsZ[cid * DD + tid] = s;
    }

    // store dS^T (layout [e][d], bf16)
    unsigned short* S = wsSh + (size_t)cid * (DD * DD);
#pragma unroll
    for (int nt = 0; nt < 4; ++nt)
#pragma unroll
        for (int j = 0; j < 4; ++j)
            S[(16 * wid + 4 * rg + j) * DD + 16 * nt + cl] = f2bf(acc[nt][j]);
}

// ---------------- Phase 2: exclusive prefix over chunks (batched loads) ----------------
__global__ __launch_bounds__(256) void k_scan(unsigned short* __restrict__ wsSh,
                                              float* __restrict__ wsZ) {
    const int blk = blockIdx.x, tid = threadIdx.x;
    if (blk < 256) {
        // S: 32 bh * 2048 dword-columns (2 bf16 each); one column per thread
        const int col = (blk << 8) + tid;          // 0..65535
        const int bh = col >> 11;                  // /2048
        unsigned int* base =
            (unsigned int*)(wsSh + (size_t)bh * NC * (DD * DD)) + (col & 2047);
        unsigned int vals[NC];
#pragma unroll
        for (int c = 0; c < NC; ++c) vals[c] = base[c * (DD * DD / 2)];
        float r0 = 0.f, r1 = 0.f;
#pragma unroll
        for (int c = 0; c < NC; ++c) {
            const unsigned int v = vals[c];
            base[c * (DD * DD / 2)] =
                (unsigned int)f2bf(r0) | ((unsigned int)f2bf(r1) << 16);
            r0 += bf2f((unsigned short)(v & 0xffffu));
            r1 += bf2f((unsigned short)(v >> 16));
        }
    } else {
        // z: 32 bh * 64 columns, fp32; blocks 256..263
        const int zi = ((blk - 256) << 8) + tid;   // 0..2047
        const int bh = zi >> 6, d = zi & 63;
        float* p = wsZ + (size_t)bh * NC * DD + d;
        float vals[NC];
#pragma unroll
        for (int c = 0; c < NC; ++c) vals[c] = p[c * DD];
        float run = 0.f;
#pragma unroll
        for (int c = 0; c < NC; ++c) {
            p[c * DD] = run;
            run += vals[c];
        }
    }
}

// ---------------- Phase 3: outputs (staging = bf16 copies except Q) ----------------
__global__ __launch_bounds__(256, 4) void k_out(const float* __restrict__ Q,
                                                const unsigned short* __restrict__ wsKb,
                                                const unsigned short* __restrict__ wsVt,
                                                const unsigned short* __restrict__ wsSh,
                                                const float* __restrict__ wsZ,
                                                float* __restrict__ O) {
    __shared__ __align__(16) unsigned short Qb[CC][LDU];   // phiQ rows
    __shared__ __align__(16) unsigned short Kb[CC][LDU];   // phiK rows; later masked scores
    __shared__ __align__(16) unsigned short Vt[DD][LDU];   // V^T rows (e-major)
    __shared__ __align__(16) unsigned short St[DD][LDU];   // S_prev^T rows (e-major)
    __shared__ float zp[DD];

    const int cid = blockIdx.x;
    const int bh = cid / NC, c = cid % NC;
    const int b = bh / HH, h = bh % HH;
    const int t0 = c * CC;
    const int tid = threadIdx.x;

    // Q: fp32 load + phi + cvt (only tensor needing compute)
#pragma unroll
    for (int w = 0; w < 4; ++w) {
        const int idx = tid + (w << 8);
        const int r = idx >> 4, q4 = (idx & 15) << 2;
        const int g = (((b * TT + t0 + r) * HH + h) << 6) + q4;
        float4 qv = *(const float4*)(Q + g);
        ushort4 us;
        us.x = f2bf(phi_f(qv.x)); us.y = f2bf(phi_f(qv.y));
        us.z = f2bf(phi_f(qv.z)); us.w = f2bf(phi_f(qv.w));
        *(ushort4*)&Qb[r][q4] = us;
    }
    // phiK, V^T, S^T: raw bf16 ushort8 copies
    {
        const size_t tb = (size_t)cid * (DD * CC);
#pragma unroll
        for (int w = 0; w < 2; ++w) {
            const int idx2 = tid + (w << 8);               // 0..511
            const int rr = idx2 >> 3, c8 = (idx2 & 7) << 3;
            *(short8*)&Kb[rr][c8] = *(const short8*)(wsKb + tb + rr * CC + c8);
            *(short8*)&Vt[rr][c8] = *(const short8*)(wsVt + tb + rr * CC + c8);
            *(short8*)&St[rr][c8] = *(const short8*)(wsSh + tb + rr * CC + c8);
        }
    }
    if (tid < 16) ((float4*)zp)[tid] = ((const float4*)(wsZ + cid * DD))[tid];
    __syncthreads();

    const int wid = tid >> 6, lane = tid & 63;
    const int rg = lane >> 4, cl = lane & 15;
    f32x4 zero4 = {0.f, 0.f, 0.f, 0.f};

    // ---- scores: D[q][kv], wave wid owns q-band 16*wid..+15; only nt <= wid
    f32x4 sc[4] = {zero4, zero4, zero4, zero4};
#pragma unroll
    for (int kk = 0; kk < 2; ++kk) {
        const short8 a = *(const short8*)&Qb[16 * wid + cl][kk * 32 + rg * 8];
        for (int nt = 0; nt <= wid; ++nt) {
            const short8 bb = *(const short8*)&Kb[16 * nt + cl][kk * 32 + rg * 8];
            sc[nt] = __builtin_amdgcn_mfma_f32_16x16x32_bf16(a, bb, sc[nt], 0, 0, 0);
        }
    }

    // ---- causal mask + row-sum den4; dint = phiQ . z_prev (lane-sliced)
    float den4[4], dint[4];
    const float4 zq = *(const float4*)&zp[4 * cl];
#pragma unroll
    for (int j = 0; j < 4; ++j) {
        const int qrow = 16 * wid + 4 * rg + j;
        float s = 0.f;
        for (int nt = 0; nt <= wid; ++nt) {
            if (16 * nt + cl > qrow) sc[nt][j] = 0.f;
            s += sc[nt][j];
        }
        den4[j] = s;
        const ushort4 qv = *(const ushort4*)&Qb[qrow][4 * cl];
        dint[j] = bf2f(qv.x) * zq.x + bf2f(qv.y) * zq.y +
                  bf2f(qv.z) * zq.z + bf2f(qv.w) * zq.w;
    }
#pragma unroll
    for (int m = 1; m < 16; m <<= 1)
#pragma unroll
        for (int j = 0; j < 4; ++j) {
            den4[j] += __shfl_xor(den4[j], m, 64);
            dint[j] += __shfl_xor(dint[j], m, 64);
        }

    // ---- inter-chunk: o = phiQ @ S_prev  (B = S^T rows)
    f32x4 oa[4] = {zero4, zero4, zero4, zero4};
#pragma unroll
    for (int kk = 0; kk < 2; ++kk) {
        const short8 a = *(const short8*)&Qb[16 * wid + cl][kk * 32 + rg * 8];
#pragma unroll
        for (int nt = 0; nt < 4; ++nt) {
            const short8 bb = *(const short8*)&St[16 * nt + cl][kk * 32 + rg * 8];
            oa[nt] = __builtin_amdgcn_mfma_f32_16x16x32_bf16(a, bb, oa[nt], 0, 0, 0);
        }
    }

    __syncthreads();   // everyone done reading Kb (scores)
    // write masked scores as bf16 into Kb; zeros for nt > wid
#pragma unroll
    for (int nt = 0; nt < 4; ++nt)
#pragma unroll
        for (int j = 0; j < 4; ++j)
            Kb[16 * wid + 4 * rg + j][16 * nt + cl] =
                (nt <= wid) ? f2bf(sc[nt][j]) : (unsigned short)0;
    __syncthreads();

    // ---- PV: o += A @ V   (A rows from Kb, B = V^T rows); kv <= 16*wid+15
    const int kkmax = (wid >= 2) ? 2 : 1;
    for (int kk = 0; kk < kkmax; ++kk) {
        const short8 a = *(const short8*)&Kb[16 * wid + cl][kk * 32 + rg * 8];
#pragma unroll
        for (int nt = 0; nt < 4; ++nt) {
            const short8 bb = *(const short8*)&Vt[16 * nt + cl][kk * 32 + rg * 8];
            oa[nt] = __builtin_amdgcn_mfma_f32_16x16x32_bf16(a, bb, oa[nt], 0, 0, 0);
        }
    }

    // ---- epilogue: divide, store (16-lane groups hit 64B segments)
#pragma unroll
    for (int j = 0; j < 4; ++j) {
        const int qrow = 16 * wid + 4 * rg + j;
        const float inv = 1.0f / (den4[j] + dint[j] + 1e-6f);
        const int gbase = (((b * TT + t0 + qrow) * HH + h) << 6);
#pragma unroll
        for (int nt = 0; nt < 4; ++nt)
            O[gbase + 16 * nt + cl] = oa[nt][j] * inv;
    }
}

extern "C" void kernel_launch(void* const* d_in, const int* in_sizes, int n_in,
                              void* d_out, int out_size, void* d_ws, size_t ws_size,
                              hipStream_t stream) {
    const float* q = (const float*)d_in[0];
    const float* k = (const float*)d_in[1];
    const float* v = (const float*)d_in[2];
    float* out = (float*)d_out;

    float* wsZ = (float*)d_ws;                                        // 256 KB fp32
    unsigned short* wsSh = (unsigned short*)(wsZ + (size_t)NCH * DD); // 8.4 MB bf16
    unsigned short* wsKb = wsSh + (size_t)NCH * DD * DD;              // 8.4 MB bf16
    unsigned short* wsVt = wsKb + (size_t)NCH * DD * CC;              // 8.4 MB bf16

    k_state<<<NCH, 256, 0, stream>>>(k, v, wsSh, wsKb, wsVt, wsZ);
    k_scan<<<264, 256, 0, stream>>>(wsSh, wsZ);
    k_out<<<NCH, 256, 0, stream>>>(q, wsKb, wsVt, wsSh, wsZ, out);
}